// Round 1
// baseline (846.719 us; speedup 1.0000x reference)
//
#include <hip/hip_runtime.h>
#include <hip/hip_bf16.h>
#include <math.h>

// GraphAttentionLayer fused kernel, MI355X (gfx950).
//
// Key identity: e (attention logit) is constant across each row, so the row
// softmax collapses to 1/cnt over unmasked entries (masked exp underflows to
// exactly 0.0f in fp32). Hence:
//   out[n,m] = adj[n,m]>0 ? elu(h[n,m]/cnt[n]) : 0,   h = X @ W
// (all-masked row: attention = 1/256 everywhere). Inputs `a` unused.
//
// GEMM is done in split-bf16 (bf16x3): X=Xh+Xl, W=Wh+Wl,
// h ~= Xh*Wh + Xh*Wl + Xl*Wh  (error ~2^-18 rel — fp32-grade), via
// mfma_f32_16x16x32_bf16, so we ride the matrix pipe instead of the 157TF
// fp32 vector ALU.

#define R_TOTAL 200000
#define K_DIM   512
#define C_DIM   256
#define BM      64
#define BK      32
#define NCHUNK  (K_DIM / BK)            // 16
#define LSTR    40                      // shorts per LDS row: 32 data + 8 pad = 80 B
#define CHUNK_BYTES (C_DIM * LSTR * 2)  // 20480 B per packed-W k-chunk
#define WPACK_BYTES (NCHUNK * CHUNK_BYTES)  // 327680 B per term

typedef __bf16 bf16x8 __attribute__((ext_vector_type(8)));
typedef __bf16 bf16x4 __attribute__((ext_vector_type(4)));
typedef float  f32x4  __attribute__((ext_vector_type(4)));

// Pre-split + transpose W into LDS-image layout: [chunk][col][k_local(+pad)].
// Runs every launch (ws is re-poisoned by the harness). ~0.2us.
__global__ void prep_w(const float* __restrict__ W,
                       __bf16* __restrict__ whi, __bf16* __restrict__ wlo) {
  int idx = blockIdx.x * 256 + threadIdx.x;   // = k*256 + c
  int k = idx >> 8, c = idx & 255;
  float w = W[idx];
  __bf16 h = (__bf16)w;
  __bf16 l = (__bf16)(w - (float)h);
  int off = ((k >> 5) * C_DIM + c) * LSTR + (k & 31);
  whi[off] = h;
  wlo[off] = l;
}

__device__ __forceinline__ void gload16(const void* g, void* l) {
  // async global->LDS, 16B/lane; LDS dest is wave-uniform base + lane*16
  __builtin_amdgcn_global_load_lds(
      (const __attribute__((address_space(1))) unsigned*)g,
      (__attribute__((address_space(3))) unsigned*)l,
      16, 0, 0);
}

__global__ void __launch_bounds__(256)
gat_kernel(const float* __restrict__ X, const int* __restrict__ adj,
           const __bf16* __restrict__ whi, const __bf16* __restrict__ wlo,
           float* __restrict__ out) {
  __shared__ __bf16 Ah[BM * LSTR];      // 5120 B
  __shared__ __bf16 Al[BM * LSTR];      // 5120 B
  __shared__ __bf16 Bh[C_DIM * LSTR];   // 20480 B
  __shared__ __bf16 Bl[C_DIM * LSTR];   // 20480 B
  __shared__ float    invl[BM];
  __shared__ unsigned maskl[BM][8];     // total LDS = 53504 B -> 3 blocks/CU

  const int tid  = threadIdx.x;
  const int lane = tid & 63;
  const int wv   = tid >> 6;   // wave 0..3 -> 2x2 wave grid
  const int wm   = wv >> 1;    // wave row (32 rows each)
  const int wn   = wv & 1;     // wave col (128 cols each)
  const int l15  = lane & 15;
  const int l4   = lane >> 4;
  const long r0  = (long)blockIdx.x * BM;

  // ---- adjacency phase: per-row count + bitmask (4 threads per row) ----
  {
    const int r = tid >> 2;    // 0..63
    const int q = tid & 3;     // 0..3, 64 ints each
    const int4* ap = (const int4*)(adj + (r0 + r) * C_DIM + q * 64);
    unsigned w0 = 0, w1 = 0;
    int cnt = 0;
#pragma unroll
    for (int j = 0; j < 16; ++j) {
      int4 v = ap[j];
      unsigned b = 0;
      b |= (v.x > 0) ? 1u : 0u;
      b |= (v.y > 0) ? 2u : 0u;
      b |= (v.z > 0) ? 4u : 0u;
      b |= (v.w > 0) ? 8u : 0u;
      cnt += __popc(b);
      if (j < 8) w0 |= b << (j * 4);
      else       w1 |= b << ((j - 8) * 4);
    }
    cnt += __shfl_xor(cnt, 1);   // quad-reduce (4 threads of one row are
    cnt += __shfl_xor(cnt, 2);   // consecutive lanes)
    if (cnt == 0) { w0 = 0xffffffffu; w1 = 0xffffffffu; }  // softmax = 1/256 everywhere
    maskl[r][q * 2]     = w0;
    maskl[r][q * 2 + 1] = w1;
    if (q == 0) invl[r] = (cnt > 0) ? (1.0f / (float)cnt) : (1.0f / 256.0f);
  }

  // ---- main GEMM loop ----
  f32x4 acc[2][8];
#pragma unroll
  for (int m = 0; m < 2; ++m)
#pragma unroll
    for (int n = 0; n < 8; ++n)
      acc[m][n] = f32x4{0.f, 0.f, 0.f, 0.f};

  const int sr = tid >> 3;   // staging: 16B-chunk row (0..31), 2 rounds
  const int sq = tid & 7;    // float4 index within the row's 32 floats

  for (int ck = 0; ck < NCHUNK; ++ck) {
    // stage A: fp32 read (coalesced 16B/lane) -> hi/lo bf16 split -> LDS
#pragma unroll
    for (int i = 0; i < 2; ++i) {
      int r = sr + i * 32;
      f32x4 v = *(const f32x4*)(X + (r0 + r) * K_DIM + ck * BK + sq * 4);
      bf16x4 hv, lv;
#pragma unroll
      for (int e = 0; e < 4; ++e) {
        float f = v[e];
        __bf16 hb = (__bf16)f;
        hv[e] = hb;
        lv[e] = (__bf16)(f - (float)hb);
      }
      *(bf16x4*)(&Ah[r * LSTR + sq * 4]) = hv;
      *(bf16x4*)(&Al[r * LSTR + sq * 4]) = lv;
    }
    // stage B: packed (pre-padded) W chunk, async global->LDS, 1KB/wave-issue
    {
      const char* srcH = (const char*)whi + ck * CHUNK_BYTES;
      const char* srcL = (const char*)wlo + ck * CHUNK_BYTES;
#pragma unroll
      for (int i = 0; i < 5; ++i) {
        int off = (wv * 5 + i) * 1024;
        gload16(srcH + off + lane * 16, (char*)Bh + off);
        gload16(srcL + off + lane * 16, (char*)Bl + off);
      }
    }
    __syncthreads();   // drains vmcnt (incl. global_load_lds) + lgkm

    bf16x8 ahf[2], alf[2];
#pragma unroll
    for (int m = 0; m < 2; ++m) {
      int row = wm * 32 + m * 16 + l15;
      ahf[m] = *(const bf16x8*)(&Ah[row * LSTR + l4 * 8]);
      alf[m] = *(const bf16x8*)(&Al[row * LSTR + l4 * 8]);
    }
#pragma unroll
    for (int n = 0; n < 8; ++n) {
      int col = wn * 128 + n * 16 + l15;
      bf16x8 bh = *(const bf16x8*)(&Bh[col * LSTR + l4 * 8]);
      bf16x8 bl = *(const bf16x8*)(&Bl[col * LSTR + l4 * 8]);
#pragma unroll
      for (int m = 0; m < 2; ++m) {
        acc[m][n] = __builtin_amdgcn_mfma_f32_16x16x32_bf16(ahf[m], bh, acc[m][n], 0, 0, 0);
        acc[m][n] = __builtin_amdgcn_mfma_f32_16x16x32_bf16(ahf[m], bl, acc[m][n], 0, 0, 0);
        acc[m][n] = __builtin_amdgcn_mfma_f32_16x16x32_bf16(alf[m], bh, acc[m][n], 0, 0, 0);
      }
    }
    __syncthreads();
  }

  // ---- fused epilogue: out = mask ? elu(h * inv) : 0 ----
#pragma unroll
  for (int m = 0; m < 2; ++m) {
#pragma unroll
    for (int n = 0; n < 8; ++n) {
      int col = wn * 128 + n * 16 + l15;
#pragma unroll
      for (int i = 0; i < 4; ++i) {
        int rl = wm * 32 + m * 16 + l4 * 4 + i;  // C/D: col=lane&15, row=(lane>>4)*4+i
        float inv = invl[rl];
        unsigned mw = maskl[rl][col >> 5];
        float h = acc[m][n][i];
        float o = 0.0f;
        if ((mw >> (col & 31)) & 1u) {
          float hp = h * inv;
          o = hp > 0.0f ? hp : expm1f(hp);
        }
        out[(r0 + rl) * C_DIM + col] = o;
      }
    }
  }
}

extern "C" void kernel_launch(void* const* d_in, const int* in_sizes, int n_in,
                              void* d_out, int out_size, void* d_ws, size_t ws_size,
                              hipStream_t stream) {
  const float* X   = (const float*)d_in[0];   // [200000,512] fp32
  const int*   adj = (const int*)d_in[1];     // [200000,256] int32
  const float* W   = (const float*)d_in[2];   // [512,256] fp32
  // d_in[3] (`a`) is mathematically unused: the rowwise softmax of a
  // row-constant logit cancels it exactly.
  __bf16* whi = (__bf16*)d_ws;
  __bf16* wlo = (__bf16*)((char*)d_ws + WPACK_BYTES);  // needs 656KB of ws

  prep_w<<<512, 256, 0, stream>>>(W, whi, wlo);
  gat_kernel<<<R_TOTAL / BM, 256, 0, stream>>>(X, adj, whi, wlo, (float*)d_out);
}